// Round 4
// baseline (835.904 us; speedup 1.0000x reference)
//
#include <hip/hip_runtime.h>
#include <cmath>

// Problem constants (from reference setup_inputs)
constexpr int B = 16, T = 2048, D = 2048, C = 100;
#define EPS_F 1e-7f

// Fused-kernel block layout
constexpr int COLSUM_BLOCKS = 1024;  // 2B(32) x T/128(16) x D/1024(2)
constexpr int SUP_BLOCKS    = 256;   // B(16) x T/128(16)
constexpr int ST_BLOCKS     = 256;   // grid-stride over B*T*C/4
constexpr int TOTAL_BLOCKS  = COLSUM_BLOCKS + SUP_BLOCKS + ST_BLOCKS;

// native clang vector type — required by __builtin_nontemporal_load
typedef float v4f __attribute__((ext_vector_type(4)));

// agent(device)-scope relaxed load: guaranteed-fresh read of cross-XCD
// atomic results in the last-block finale (L1/L2 coherence handled by scope)
__device__ __forceinline__ float aload(const float* p) {
    return __hip_atomic_load(p, __ATOMIC_RELAXED, __HIP_MEMORY_SCOPE_AGENT);
}

__device__ __forceinline__ float block_reduce(float v, volatile float* s4) {
    for (int off = 32; off; off >>= 1) v += __shfl_down(v, off, 64);
    int lane = threadIdx.x & 63, wv = threadIdx.x >> 6;
    __syncthreads();               // protect s4 against previous use
    if (lane == 0) s4[wv] = v;
    __syncthreads();
    return s4[0] + s4[1] + s4[2] + s4[3];
}

// ---------------------------------------------------------------------------
// ONE kernel: colsum (537 MB) + sup (52 MB) + st (26 MB) blocks run
// concurrently; the last block to finish (device-scope counter) computes all
// scalar losses and writes out[6].
// ---------------------------------------------------------------------------
__global__ __launch_bounds__(256) void fused_kernel(
        const float* __restrict__ feat_act, const float* __restrict__ feat_bkg,
        const float* __restrict__ gt,       const float* __restrict__ sup,
        const float* __restrict__ cas_s,    const float* __restrict__ cas_t,
        const float* __restrict__ score_act,
        const float* __restrict__ score_bkg,
        const float* __restrict__ label,
        float* __restrict__ ws, float* __restrict__ out) {
    // ws layout (floats): colsum[2B*D] | sup_sumsq[B*C] | sup_cnt[B*C] |
    //                     st_acc[1] | counter (as uint)
    float* colsum    = ws;
    float* sup_sumsq = ws + (size_t)2 * B * D;
    float* sup_cnt   = sup_sumsq + B * C;
    float* st_acc    = sup_cnt + B * C;
    unsigned* counter = reinterpret_cast<unsigned*>(st_acc + 1);

    __shared__ float s4[4];
    __shared__ float rowsum[B];
    __shared__ float an[B], bn[B];
    __shared__ int s_last;

    const int tid = threadIdx.x;
    const int bid = blockIdx.x;

    if (bid < COLSUM_BLOCKS) {
        // ---- column sum over a 128-row chunk, 16B nontemporal loads ----
        const int z   = bid >> 5;          // 0..31 (tensor*batch)
        const int rem = bid & 31;
        const int tch = rem >> 1;          // 0..15 t-chunk
        const int xh  = rem & 1;           // 0..1 d-half
        const float* feat = (z < B) ? feat_act : feat_bkg;
        const int b  = (z < B) ? z : z - B;
        const int d0 = (xh * 256 + tid) * 4;
        const int t0 = tch * 128;
        const float* base = feat + ((size_t)b * T + t0) * D + d0;
        v4f acc = (v4f)(0.f);
#pragma unroll 8
        for (int t = 0; t < 128; ++t)
            acc += __builtin_nontemporal_load(
                reinterpret_cast<const v4f*>(base + (size_t)t * D));
        float* o = colsum + (size_t)z * D + d0;
        atomicAdd(o + 0, acc.x);
        atomicAdd(o + 1, acc.y);
        atomicAdd(o + 2, acc.z);
        atomicAdd(o + 3, acc.w);
    } else if (bid < COLSUM_BLOCKS + SUP_BLOCKS) {
        // ---- per-(b,c) sup stats over a 128-row chunk ----
        const int s   = bid - COLSUM_BLOCKS;
        const int b   = s >> 4;            // 0..15
        const int tch = s & 15;            // 0..15
        const int j   = tid & 31;          // class quad
        const int r   = tid >> 5;          // row slot 0..7
        if (j < C / 4) {
            const int t0 = tch * 128 + r;
            size_t base = ((size_t)b * T + t0) * C + 4 * j;
            v4f acc = (v4f)(0.f);
            v4f pc  = (v4f)(0.f);
#pragma unroll
            for (int t = 0; t < 128; t += 8) {
                v4f g = __builtin_nontemporal_load(
                    reinterpret_cast<const v4f*>(gt  + base + (size_t)t * C));
                v4f sv = __builtin_nontemporal_load(
                    reinterpret_cast<const v4f*>(sup + base + (size_t)t * C));
                float m, d;
                m = (g.x > 0.5f) ? 1.f : 0.f; d = sv.x - m; acc.x += d * d; pc.x += m;
                m = (g.y > 0.5f) ? 1.f : 0.f; d = sv.y - m; acc.y += d * d; pc.y += m;
                m = (g.z > 0.5f) ? 1.f : 0.f; d = sv.z - m; acc.z += d * d; pc.z += m;
                m = (g.w > 0.5f) ? 1.f : 0.f; d = sv.w - m; acc.w += d * d; pc.w += m;
            }
            float* sq = sup_sumsq + b * C + 4 * j;
            float* ct = sup_cnt   + b * C + 4 * j;
            atomicAdd(sq + 0, acc.x); atomicAdd(sq + 1, acc.y);
            atomicAdd(sq + 2, acc.z); atomicAdd(sq + 3, acc.w);
            atomicAdd(ct + 0, pc.x);  atomicAdd(ct + 1, pc.y);
            atomicAdd(ct + 2, pc.z);  atomicAdd(ct + 3, pc.w);
        }
    } else {
        // ---- st: sum of (cas_s - cas_t)^2, grid-stride ----
        const int n4 = (B * T * C) / 4;    // 819200
        int idx = (bid - COLSUM_BLOCKS - SUP_BLOCKS) * 256 + tid;
        float local = 0.f;
        for (int i = idx; i < n4; i += ST_BLOCKS * 256) {
            v4f a  = __builtin_nontemporal_load(
                reinterpret_cast<const v4f*>(cas_s) + i);
            v4f b4 = __builtin_nontemporal_load(
                reinterpret_cast<const v4f*>(cas_t) + i);
            v4f d = a - b4;
            local += d.x * d.x + d.y * d.y + d.z * d.z + d.w * d.w;
        }
        for (int off = 32; off; off >>= 1) local += __shfl_down(local, off, 64);
        int lane = tid & 63, wv = tid >> 6;
        if (lane == 0) s4[wv] = local;
        __syncthreads();
        if (tid == 0) atomicAdd(st_acc, s4[0] + s4[1] + s4[2] + s4[3]);
    }

    // ---- last-block-done: device-scope release/acquire via counter ----
    __threadfence();
    __syncthreads();
    if (tid == 0)
        s_last = (atomicAdd(counter, 1u) == (unsigned)(TOTAL_BLOCKS - 1)) ? 1 : 0;
    __syncthreads();
    if (!s_last) return;
    __threadfence();   // acquire side

    // ================= finale (one block, 256 threads) =================
    const int N = B * C;

    if (tid < B) rowsum[tid] = 0.f;
    __syncthreads();
    for (int i = tid; i < N; i += 256) atomicAdd(&rowsum[i / C], label[i]);
    __syncthreads();

    // loss_cls: BCE(score_act, label / rowsum)
    float lc = 0.f;
    for (int i = tid; i < N; i += 256) {
        float tgt = label[i] / rowsum[i / C];
        float p = fminf(fmaxf(score_act[i], EPS_F), 1.f - EPS_F);
        lc -= tgt * logf(p) + (1.f - tgt) * log1pf(-p);
    }
    float loss_cls = block_reduce(lc, s4) / (float)N;

    // loss_be: BCE(score_bkg, 1/C)
    float lb = 0.f;
    const float u = 1.f / (float)C;
    for (int i = tid; i < N; i += 256) {
        float p = fminf(fmaxf(score_bkg[i], EPS_F), 1.f - EPS_F);
        lb -= u * logf(p) + (1.f - u) * log1pf(-p);
    }
    float loss_be = block_reduce(lb, s4) / (float)N;

    // norms of mean features (agent-scope loads of atomically-built colsum)
    const float invT = 1.f / (float)T;
    for (int b = 0; b < B; ++b) {
        float la = 0.f, lg = 0.f;
        for (int d = tid; d < D; d += 256) {
            float va = aload(colsum + (size_t)b * D + d) * invT;
            float vb = aload(colsum + (size_t)(b + B) * D + d) * invT;
            la += va * va;
            lg += vb * vb;
        }
        float sa = block_reduce(la, s4);
        float sb = block_reduce(lg, s4);
        if (tid == 0) { an[b] = sqrtf(sa); bn[b] = sqrtf(sb); }
    }
    __syncthreads();

    // loss_sup
    float ss = 0.f, sc = 0.f;
    for (int i = tid; i < N; i += 256) {
        if (aload(sup_cnt + i) > 0.f) { ss += sqrtf(aload(sup_sumsq + i)); sc += 1.f; }
    }
    float sup_sum   = block_reduce(ss, s4);
    float sup_count = block_reduce(sc, s4);

    if (tid == 0) {
        float loss_um = 0.f;
        for (int b = 0; b < B; ++b) {
            float la = fmaxf(100.f - an[b], 0.f);
            float v = la + bn[b];
            loss_um += v * v;
        }
        loss_um /= (float)B;
        float loss_sup = sup_sum / fmaxf(sup_count, 1.f);
        float loss_st = aload(st_acc) / (float)((size_t)B * T * C);
        float total = loss_cls + 0.0005f * loss_um + 1.0f * loss_be
                    + 1.0f * loss_sup + 1.0f * loss_st;
        out[0] = total;
        out[1] = loss_cls;
        out[2] = loss_be;
        out[3] = loss_um;
        out[4] = loss_sup;
        out[5] = loss_st;
    }
}

// ---------------------------------------------------------------------------
extern "C" void kernel_launch(void* const* d_in, const int* in_sizes, int n_in,
                              void* d_out, int out_size, void* d_ws, size_t ws_size,
                              hipStream_t stream) {
    const float* score_act = (const float*)d_in[0];
    const float* score_bkg = (const float*)d_in[1];
    const float* feat_act  = (const float*)d_in[2];
    const float* feat_bkg  = (const float*)d_in[3];
    const float* label     = (const float*)d_in[4];
    const float* gt        = (const float*)d_in[5];
    const float* sup_cas   = (const float*)d_in[6];
    const float* cas_s     = (const float*)d_in[7];
    const float* cas_t     = (const float*)d_in[8];
    float* out = (float*)d_out;
    float* ws  = (float*)d_ws;

    // ws: colsum[2B*D] | sup_sumsq[B*C] | sup_cnt[B*C] | st_acc[1] | counter[1]
    size_t ws_needed = ((size_t)2 * B * D + 2 * B * C + 2) * sizeof(float);
    (void)hipMemsetAsync(d_ws, 0, ws_needed, stream);

    fused_kernel<<<TOTAL_BLOCKS, 256, 0, stream>>>(
        feat_act, feat_bkg, gt, sup_cas, cas_s, cas_t,
        score_act, score_bkg, label, ws, out);
}